// Round 1
// baseline (3273.658 us; speedup 1.0000x reference)
//
#include <hip/hip_runtime.h>
#include <math.h>

#define NF 500   // input features
#define NH 256   // hidden
#define NC 40    // classes
#define KIT 10   // AMP iterations
#define LAMW 0.5f

// ---------------- fused MLP: h = relu(x@W1+b1)@W2+b2 ----------------
// 64 rows/block, 256 threads. Phase1: 4x16 register tile per thread over
// K-tiles of 20 staged in LDS. Phase2: H1 tile (64x256) in LDS, W2 from L1.
__global__ __launch_bounds__(256, 2) void mlp_kernel(
    const float* __restrict__ x, const float* __restrict__ W1,
    const float* __restrict__ b1, const float* __restrict__ W2,
    const float* __restrict__ b2, float* __restrict__ hout, int N)
{
    __shared__ float smem[64 * 256];           // 64KB; phase1 carves Xs+W1s, phase2 = Hs
    float* Xs  = smem;                         // [64][21] padded
    float* W1s = smem + 64 * 21;               // [20][256]
    const int t  = threadIdx.x;
    const int tr = t >> 4;                     // 0..15 row group
    const int tc = t & 15;                     // 0..15 col group
    const int row0 = blockIdx.x * 64;

    float acc[4][16];
    #pragma unroll
    for (int i = 0; i < 4; i++)
        #pragma unroll
        for (int j = 0; j < 16; j++) acc[i][j] = 0.f;

    for (int k0 = 0; k0 < NF; k0 += 20) {
        // stage X tile 64x20 (coalesced-ish scalar)
        for (int idx = t; idx < 64 * 20; idx += 256) {
            int r = idx / 20, k = idx - r * 20;
            int gr = row0 + r;
            Xs[r * 21 + k] = (gr < N) ? x[(size_t)gr * NF + k0 + k] : 0.f;
        }
        // stage W1 tile 20x256 (fully coalesced)
        #pragma unroll
        for (int i = 0; i < 20; i++)
            W1s[i * 256 + t] = W1[(size_t)(k0 + i) * NH + t];
        __syncthreads();
        #pragma unroll
        for (int kk = 0; kk < 20; kk++) {
            float xa[4];
            #pragma unroll
            for (int i = 0; i < 4; i++) xa[i] = Xs[(tr * 4 + i) * 21 + kk];
            const float4* wr = (const float4*)&W1s[kk * 256 + tc * 16];
            float4 wq0 = wr[0], wq1 = wr[1], wq2 = wr[2], wq3 = wr[3];
            float wv[16];
            wv[0]=wq0.x; wv[1]=wq0.y; wv[2]=wq0.z; wv[3]=wq0.w;
            wv[4]=wq1.x; wv[5]=wq1.y; wv[6]=wq1.z; wv[7]=wq1.w;
            wv[8]=wq2.x; wv[9]=wq2.y; wv[10]=wq2.z; wv[11]=wq2.w;
            wv[12]=wq3.x; wv[13]=wq3.y; wv[14]=wq3.z; wv[15]=wq3.w;
            #pragma unroll
            for (int i = 0; i < 4; i++)
                #pragma unroll
                for (int j = 0; j < 16; j++) acc[i][j] += xa[i] * wv[j];
        }
        __syncthreads();   // also protects smem reuse below on last iter
    }
    // bias + relu -> Hs (plain [64][256] layout)
    const float4* bp = (const float4*)&b1[tc * 16];
    float4 bq0 = bp[0], bq1 = bp[1], bq2 = bp[2], bq3 = bp[3];
    float bb[16];
    bb[0]=bq0.x; bb[1]=bq0.y; bb[2]=bq0.z; bb[3]=bq0.w;
    bb[4]=bq1.x; bb[5]=bq1.y; bb[6]=bq1.z; bb[7]=bq1.w;
    bb[8]=bq2.x; bb[9]=bq2.y; bb[10]=bq2.z; bb[11]=bq2.w;
    bb[12]=bq3.x; bb[13]=bq3.y; bb[14]=bq3.z; bb[15]=bq3.w;
    #pragma unroll
    for (int i = 0; i < 4; i++) {
        #pragma unroll
        for (int jj = 0; jj < 4; jj++) {
            float4 v;
            v.x = fmaxf(acc[i][4*jj+0] + bb[4*jj+0], 0.f);
            v.y = fmaxf(acc[i][4*jj+1] + bb[4*jj+1], 0.f);
            v.z = fmaxf(acc[i][4*jj+2] + bb[4*jj+2], 0.f);
            v.w = fmaxf(acc[i][4*jj+3] + bb[4*jj+3], 0.f);
            *(float4*)&smem[(tr * 4 + i) * 256 + tc * 16 + jj * 4] = v;
        }
    }
    __syncthreads();
    // phase 2: each thread does 1 row x 10 cols of [64 x 40]
    const int r2 = t >> 2;     // 0..63
    const int g  = t & 3;      // 0..3 -> cols g*10..g*10+9
    float acc2[10];
    #pragma unroll
    for (int o = 0; o < 10; o++) acc2[o] = b2[g * 10 + o];
    #pragma unroll 4
    for (int s = 0; s < 64; s++) {
        int q = (r2 + s) & 63;                      // rotate to spread LDS banks
        float4 hv4 = *(const float4*)&smem[r2 * 256 + q * 4];
        const float* hvp = (const float*)&hv4;
        #pragma unroll
        for (int jj = 0; jj < 4; jj++) {
            float hv = hvp[jj];
            const float2* w2p = (const float2*)&W2[(size_t)(q * 4 + jj) * NC + g * 10];
            #pragma unroll
            for (int p = 0; p < 5; p++) {
                float2 wv2 = w2p[p];
                acc2[2*p]   += hv * wv2.x;
                acc2[2*p+1] += hv * wv2.y;
            }
        }
    }
    int n = row0 + r2;
    if (n < N) {
        #pragma unroll
        for (int o = 0; o < 10; o++) hout[(size_t)n * NC + g * 10 + o] = acc2[o];
    }
}

// ---------------- degree / norm setup ----------------
__global__ void init_one_kernel(float* p, int N) {
    int i = blockIdx.x * 256 + threadIdx.x;
    if (i < N) p[i] = 1.0f;                    // self-loop contributes 1 to degree
}
__global__ void deg_edges_kernel(const int* __restrict__ dst, float* deg, int E) {
    int e = blockIdx.x * 256 + threadIdx.x;
    if (e < E) atomicAdd(&deg[dst[e]], 1.0f);
}
__global__ void rsqrt_kernel(float* p, int N) {
    int i = blockIdx.x * 256 + threadIdx.x;
    if (i < N) p[i] = rsqrtf(p[i]);            // deg >= 1 always
}
__global__ void zero_int_kernel(int* p, int N) {
    int i = blockIdx.x * 256 + threadIdx.x;
    if (i < N) p[i] = 0;
}
__global__ void cnt_edges_kernel(const int* __restrict__ dst, int* cnt, int E) {
    int e = blockIdx.x * 256 + threadIdx.x;
    if (e < E) atomicAdd(&cnt[dst[e]], 1);
}

// ---------------- exclusive scan (3 passes) ----------------
__global__ __launch_bounds__(1024) void scanA_kernel(
    const int* __restrict__ cnt, int* __restrict__ rowptr, int* __restrict__ bsum, int N)
{
    __shared__ int sd[1024];
    int t = threadIdx.x;
    int i = blockIdx.x * 1024 + t;
    sd[t] = (i < N) ? cnt[i] : 0;
    __syncthreads();
    for (int off = 1; off < 1024; off <<= 1) {
        int v = (t >= off) ? sd[t - off] : 0;
        __syncthreads();
        if (t >= off) sd[t] += v;
        __syncthreads();
    }
    if (i < N) rowptr[i + 1] = sd[t];          // inclusive, shifted
    if (t == 1023) bsum[blockIdx.x] = sd[1023];
}
__global__ void scanB_kernel(int* bsum, int nb) {   // nb <= 256
    __shared__ int sb[256];
    int t = threadIdx.x;
    sb[t] = (t < nb) ? bsum[t] : 0;
    __syncthreads();
    if (t == 0) { int run = 0; for (int i = 0; i < nb; i++) { int v = sb[i]; sb[i] = run; run += v; } }
    __syncthreads();
    if (t < nb) bsum[t] = sb[t];
}
__global__ __launch_bounds__(1024) void scanC_kernel(int* rowptr, const int* __restrict__ bpre, int N) {
    int i = blockIdx.x * 1024 + threadIdx.x;
    if (i < N) rowptr[i + 1] += bpre[blockIdx.x];
    if (i == 0) rowptr[0] = 0;
}
__global__ void copy_int_kernel(int* dstp, const int* __restrict__ srcp, int N) {
    int i = blockIdx.x * 256 + threadIdx.x;
    if (i < N) dstp[i] = srcp[i];
}
__global__ void fill_csr_kernel(const int* __restrict__ src, const int* __restrict__ dst,
    const float* __restrict__ dinv, int* cursor, int* __restrict__ csrs,
    float* __restrict__ csrw, int E)
{
    int e = blockIdx.x * 256 + threadIdx.x;
    if (e < E) {
        int d = dst[e], s = src[e];
        int p = atomicAdd(&cursor[d], 1);
        csrs[p] = s;
        csrw[p] = dinv[s] * dinv[d];
    }
}

// ---------------- fused AMP iteration (gather SpMM + L21 prox) ----------------
// block = (40,16): 16 nodes/block, one feature per threadIdx.x
__global__ __launch_bounds__(640, 1) void amp_kernel(
    const float* __restrict__ xk, const float* __restrict__ hh,
    const int* __restrict__ rowptr, const int* __restrict__ csrs,
    const float* __restrict__ csrw, const float* __restrict__ dinv,
    float* __restrict__ xk_new, float* __restrict__ lsm_out,
    float* __restrict__ score_out, int N, int last)
{
    const int tx = threadIdx.x;   // 0..39 feature
    const int ty = threadIdx.y;   // 0..15 node slot
    const int n = blockIdx.x * 16 + ty;
    __shared__ float red[16][48];
    __shared__ float sval[16];
    bool valid = (n < N);
    float di = valid ? dinv[n] : 0.f;
    float xo = valid ? xk[(size_t)n * NC + tx] : 0.f;
    float acc = di * di * xo;                       // self-loop term
    int e0 = valid ? rowptr[n] : 0;
    int e1 = valid ? rowptr[n + 1] : 0;
    for (int e = e0; e < e1; ++e) {
        int s = csrs[e];                            // broadcast across the 40 lanes
        acc += csrw[e] * xk[(size_t)s * NC + tx];   // 160B contiguous row gather
    }
    float hv = valid ? hh[(size_t)n * NC + tx] : 0.f;
    float diff = acc - hv;                          // y = prop (coef==1.0 exactly)
    red[ty][tx] = diff * diff;
    __syncthreads();
    if (tx == 0) {
        float ssum = 0.f;
        for (int i = 0; i < NC; i++) ssum += red[ty][i];
        float rn = sqrtf(ssum);
        float sc = (rn > LAMW) ? (rn - LAMW) / rn : 0.f;
        sval[ty] = sc;
        if (last && valid) score_out[n] = sc;
    }
    __syncthreads();
    float xn = hv + sval[ty] * diff;
    if (!last) {
        if (valid) xk_new[(size_t)n * NC + tx] = xn;
    } else {
        red[ty][tx] = xn;
        __syncthreads();
        if (tx == 0) {
            float m = -1e30f;
            for (int i = 0; i < NC; i++) m = fmaxf(m, red[ty][i]);
            float se = 0.f;
            for (int i = 0; i < NC; i++) se += expf(red[ty][i] - m);
            sval[ty] = m + logf(se);
        }
        __syncthreads();
        if (valid) lsm_out[(size_t)n * NC + tx] = xn - sval[ty];
    }
}

extern "C" void kernel_launch(void* const* d_in, const int* in_sizes, int n_in,
                              void* d_out, int out_size, void* d_ws, size_t ws_size,
                              hipStream_t stream)
{
    const float* x  = (const float*)d_in[0];
    const float* W1 = (const float*)d_in[1];
    const float* b1 = (const float*)d_in[2];
    const float* W2 = (const float*)d_in[3];
    const float* b2 = (const float*)d_in[4];
    const int* esrc = (const int*)d_in[5];
    const int* edst = (const int*)d_in[6];
    const int N = in_sizes[0] / NF;
    const int E = in_sizes[5];

    // workspace carve (~62.5 MB total)
    size_t ncf = (size_t)N * NC;
    float* hh   = (float*)d_ws;          // [N,40] MLP output == hh
    float* xb0  = hh + ncf;              // ping
    float* xb1  = xb0 + ncf;             // pong
    float* dinv = xb1 + ncf;             // degree -> rsqrt, in place
    int* rowptr = (int*)(dinv + N);      // N+1
    int* cnt    = rowptr + (N + 1);      // N (reused as CSR cursor)
    int* bsum   = cnt + N;               // scan block sums
    int* csrs   = bsum + 256;            // E
    float* csrw = (float*)(csrs + E);    // E

    float* lsm = (float*)d_out;          // [N,40] log_softmax
    float* sco = lsm + ncf;              // [N] score

    const int gb = (N + 255) / 256;
    const int ge = (E + 255) / 256;
    const int nb = (N + 1023) / 1024;

    mlp_kernel<<<(N + 63) / 64, 256, 0, stream>>>(x, W1, b1, W2, b2, hh, N);

    init_one_kernel<<<gb, 256, 0, stream>>>(dinv, N);
    deg_edges_kernel<<<ge, 256, 0, stream>>>(edst, dinv, E);
    rsqrt_kernel<<<gb, 256, 0, stream>>>(dinv, N);

    zero_int_kernel<<<gb, 256, 0, stream>>>(cnt, N);
    cnt_edges_kernel<<<ge, 256, 0, stream>>>(edst, cnt, E);
    scanA_kernel<<<nb, 1024, 0, stream>>>(cnt, rowptr, bsum, N);
    scanB_kernel<<<1, 256, 0, stream>>>(bsum, nb);
    scanC_kernel<<<nb, 1024, 0, stream>>>(rowptr, bsum, N);
    copy_int_kernel<<<gb, 256, 0, stream>>>(cnt, rowptr, N);   // cursor
    fill_csr_kernel<<<ge, 256, 0, stream>>>(esrc, edst, dinv, cnt, csrs, csrw, E);

    const float* xold = hh;
    float* bufs[2] = {xb0, xb1};
    for (int k = 0; k < KIT; k++) {
        int last = (k == KIT - 1);
        float* xnew = bufs[k & 1];
        amp_kernel<<<(N + 15) / 16, dim3(40, 16), 0, stream>>>(
            xold, hh, rowptr, csrs, csrw, dinv, xnew, lsm, sco, N, last);
        xold = xnew;
    }
}

// Round 3
// 1655.875 us; speedup vs baseline: 1.9770x; 1.9770x over previous
//
#include <hip/hip_runtime.h>
#include <math.h>

#define NF 500
#define KPAD 512
#define NH 256
#define NC 40
#define NCPAD 48
#define KIT 10
#define LAMW 0.5f

typedef __attribute__((ext_vector_type(8))) short short8;
typedef __attribute__((ext_vector_type(4))) float f32x4;

__device__ __forceinline__ unsigned short bf_rne(float v) {
    unsigned int b = __float_as_uint(v);
    unsigned int h = (b + 0x7FFFu + ((b >> 16) & 1u)) >> 16;
    return (unsigned short)h;
}

// ---------------- weight prepass: transpose + bf16 hi/lo split ----------------
__global__ void w1prep_kernel(const float* __restrict__ W1, unsigned short* __restrict__ H,
                              unsigned short* __restrict__ L) {
    int k = blockIdx.x;        // 0..511
    int c = threadIdx.x;       // 0..255
    float v = (k < NF) ? W1[(size_t)k * NH + c] : 0.f;
    unsigned short h = bf_rne(v);
    float hf = __uint_as_float(((unsigned int)h) << 16);
    unsigned short lo = bf_rne(v - hf);
    H[(size_t)c * KPAD + k] = h;
    L[(size_t)c * KPAD + k] = lo;
}
__global__ void w2prep_kernel(const float* __restrict__ W2, unsigned short* __restrict__ H,
                              unsigned short* __restrict__ L) {
    int c = blockIdx.x;        // 0..47
    int k = threadIdx.x;       // 0..255
    float v = (c < NC) ? W2[(size_t)k * NC + c] : 0.f;
    unsigned short h = bf_rne(v);
    float hf = __uint_as_float(((unsigned int)h) << 16);
    unsigned short lo = bf_rne(v - hf);
    H[(size_t)c * NH + k] = h;
    L[(size_t)c * NH + k] = lo;
}

// ---------------- fused MLP via split-bf16 MFMA ----------------
// block = 256 thr (4 waves), 64 rows/block.
// GEMM1: [64 x 512] @ [512 x 256]; wave w owns cols 64w..64w+63 (4x4 fragtile).
// GEMM2 (out^T): A=W2t [48 x 256], B=h1^T via LDS [64][256]; wave w owns nodes 16w..16w+15.
__global__ __launch_bounds__(256, 2) void mlp_mfma_kernel(
    const float* __restrict__ x, const float* __restrict__ b1,
    const unsigned short* __restrict__ W1tH, const unsigned short* __restrict__ W1tL,
    const unsigned short* __restrict__ W2tH, const unsigned short* __restrict__ W2tL,
    const float* __restrict__ b2, float* __restrict__ hout, int N)
{
    __shared__ unsigned short smem[33792];     // 67.6 KB, phase1 A / phase2 H union
    unsigned short* Ahi = smem;                // [64][40] (pad 32->40: 2-way banks max)
    unsigned short* Alo = smem + 64 * 40;
    unsigned short* Hhi = smem;                // [64][264]
    unsigned short* Hlo = smem + 64 * 264;

    const int t   = threadIdx.x;
    const int w   = t >> 6;
    const int l   = t & 63;
    const int l15 = l & 15;
    const int lq  = l >> 4;
    const int row0 = blockIdx.x * 64;

    f32x4 acc[4][4];
    #pragma unroll
    for (int r = 0; r < 4; r++)
        #pragma unroll
        for (int c = 0; c < 4; c++) acc[r][c] = (f32x4){0.f, 0.f, 0.f, 0.f};

    const int srow = t >> 2;          // staging row 0..63
    const int skof = (t & 3) * 8;     // staging k-offset 0/8/16/24
    const int gr = row0 + srow;

    float v[8];
    // prologue: load k-tile 0
    {
        const float* p = x + (size_t)gr * NF;
        if (gr < N) {
            float4 a = *(const float4*)(p + skof);
            float4 b = *(const float4*)(p + skof + 4);
            v[0]=a.x; v[1]=a.y; v[2]=a.z; v[3]=a.w; v[4]=b.x; v[5]=b.y; v[6]=b.z; v[7]=b.w;
        } else {
            #pragma unroll
            for (int j = 0; j < 8; j++) v[j] = 0.f;
        }
    }

    const size_t bB = (size_t)(64 * w + l15) * KPAD + lq * 8;   // W1t lane base
    for (int kt = 0; kt < 16; ++kt) {
        __syncthreads();
        // convert + store A tile
        {
            short8 sh, sl;
            #pragma unroll
            for (int j = 0; j < 8; j++) {
                unsigned int b = __float_as_uint(v[j]);
                unsigned int h = (b + 0x7FFFu + ((b >> 16) & 1u)) >> 16;
                float hf = __uint_as_float(h << 16);
                float rr = v[j] - hf;
                unsigned int rb = __float_as_uint(rr);
                unsigned int lo = (rb + 0x7FFFu + ((rb >> 16) & 1u)) >> 16;
                sh[j] = (short)h; sl[j] = (short)lo;
            }
            *(short8*)&Ahi[srow * 40 + skof] = sh;
            *(short8*)&Alo[srow * 40 + skof] = sl;
        }
        __syncthreads();
        // prefetch next x tile (hides HBM under MFMA)
        if (kt < 15) {
            int k = (kt + 1) * 32 + skof;
            if (gr < N && kt + 1 < 15) {
                const float* p = x + (size_t)gr * NF + k;
                float4 a = *(const float4*)p;
                float4 b = *(const float4*)(p + 4);
                v[0]=a.x; v[1]=a.y; v[2]=a.z; v[3]=a.w; v[4]=b.x; v[5]=b.y; v[6]=b.z; v[7]=b.w;
            } else {
                #pragma unroll
                for (int j = 0; j < 8; j++)
                    v[j] = (gr < N && k + j < NF) ? x[(size_t)gr * NF + k + j] : 0.f;
            }
        }
        // fragments
        short8 ah[4], al[4], bh[4], bl[4];
        #pragma unroll
        for (int r = 0; r < 4; r++) {
            ah[r] = *(short8*)&Ahi[(16 * r + l15) * 40 + lq * 8];
            al[r] = *(short8*)&Alo[(16 * r + l15) * 40 + lq * 8];
        }
        #pragma unroll
        for (int c = 0; c < 4; c++) {
            bh[c] = *(const short8*)&W1tH[bB + (size_t)c * 16 * KPAD + kt * 32];
            bl[c] = *(const short8*)&W1tL[bB + (size_t)c * 16 * KPAD + kt * 32];
        }
        #pragma unroll
        for (int c = 0; c < 4; c++)
            #pragma unroll
            for (int r = 0; r < 4; r++) {
                acc[r][c] = __builtin_amdgcn_mfma_f32_16x16x32_bf16(ah[r], bh[c], acc[r][c], 0, 0, 0);
                acc[r][c] = __builtin_amdgcn_mfma_f32_16x16x32_bf16(al[r], bh[c], acc[r][c], 0, 0, 0);
                acc[r][c] = __builtin_amdgcn_mfma_f32_16x16x32_bf16(ah[r], bl[c], acc[r][c], 0, 0, 0);
            }
    }
    __syncthreads();   // done with A region before H overwrite

    // bias + relu + hi/lo split -> H LDS
    #pragma unroll
    for (int c = 0; c < 4; c++) {
        int col = 64 * w + 16 * c + l15;
        float bb = b1[col];
        #pragma unroll
        for (int r = 0; r < 4; r++) {
            #pragma unroll
            for (int g = 0; g < 4; g++) {
                float hval = fmaxf(acc[r][c][g] + bb, 0.f);
                unsigned int hb = __float_as_uint(hval);
                unsigned int h = (hb + 0x7FFFu + ((hb >> 16) & 1u)) >> 16;
                float hf = __uint_as_float(h << 16);
                float rr = hval - hf;
                unsigned int rb = __float_as_uint(rr);
                unsigned int lo = (rb + 0x7FFFu + ((rb >> 16) & 1u)) >> 16;
                int rowi = 16 * r + lq * 4 + g;
                Hhi[rowi * 264 + col] = (unsigned short)h;
                Hlo[rowi * 264 + col] = (unsigned short)lo;
            }
        }
    }
    __syncthreads();

    // GEMM2: out^T = W2t @ h1^T  (per wave: 16 nodes, 48 classes)
    f32x4 acc2[3];
    #pragma unroll
    for (int cf = 0; cf < 3; cf++) acc2[cf] = (f32x4){0.f, 0.f, 0.f, 0.f};
    const int hbase = (16 * w + l15) * 264 + lq * 8;
    const int wbase = l15 * NH + lq * 8;
    #pragma unroll
    for (int kt = 0; kt < 8; ++kt) {
        short8 bh = *(short8*)&Hhi[hbase + kt * 32];
        short8 bl = *(short8*)&Hlo[hbase + kt * 32];
        #pragma unroll
        for (int cf = 0; cf < 3; cf++) {
            short8 awh = *(const short8*)&W2tH[wbase + cf * 16 * NH + kt * 32];
            short8 awl = *(const short8*)&W2tL[wbase + cf * 16 * NH + kt * 32];
            acc2[cf] = __builtin_amdgcn_mfma_f32_16x16x32_bf16(awh, bh, acc2[cf], 0, 0, 0);
            acc2[cf] = __builtin_amdgcn_mfma_f32_16x16x32_bf16(awl, bh, acc2[cf], 0, 0, 0);
            acc2[cf] = __builtin_amdgcn_mfma_f32_16x16x32_bf16(awh, bl, acc2[cf], 0, 0, 0);
        }
    }
    int node = row0 + 16 * w + l15;
    if (node < N) {
        #pragma unroll
        for (int cf = 0; cf < 3; cf++) {
            #pragma unroll
            for (int g = 0; g < 4; g++) {
                int cls = 16 * cf + lq * 4 + g;
                if (cls < NC) hout[(size_t)node * NC + cls] = acc2[cf][g] + b2[cls];
            }
        }
    }
}

// ---------------- setup ----------------
__global__ void zero_int_kernel(int* p, int N) {
    int i = blockIdx.x * 256 + threadIdx.x;
    if (i < N) p[i] = 0;
}
__global__ void cnt_edges_kernel(const int* __restrict__ dst, int* cnt, int E) {
    int e = blockIdx.x * 256 + threadIdx.x;
    if (e < E) atomicAdd(&cnt[dst[e]], 1);
}
__global__ void dinv_kernel(const int* __restrict__ cnt, float* dinv, int N) {
    int i = blockIdx.x * 256 + threadIdx.x;
    if (i < N) dinv[i] = rsqrtf((float)cnt[i] + 1.0f);
}
__global__ __launch_bounds__(1024) void scanA_kernel(
    const int* __restrict__ cnt, int* __restrict__ rowptr, int* __restrict__ bsum, int N)
{
    __shared__ int sd[1024];
    int t = threadIdx.x;
    int i = blockIdx.x * 1024 + t;
    sd[t] = (i < N) ? cnt[i] : 0;
    __syncthreads();
    for (int off = 1; off < 1024; off <<= 1) {
        int v = (t >= off) ? sd[t - off] : 0;
        __syncthreads();
        if (t >= off) sd[t] += v;
        __syncthreads();
    }
    if (i < N) rowptr[i + 1] = sd[t];
    if (t == 1023) bsum[blockIdx.x] = sd[1023];
}
__global__ void scanB_kernel(int* bsum, int nb) {
    __shared__ int sb[256];
    int t = threadIdx.x;
    sb[t] = (t < nb) ? bsum[t] : 0;
    __syncthreads();
    if (t == 0) { int run = 0; for (int i = 0; i < nb; i++) { int v = sb[i]; sb[i] = run; run += v; } }
    __syncthreads();
    if (t < nb) bsum[t] = sb[t];
}
__global__ __launch_bounds__(1024) void scanC_kernel(int* rowptr, const int* __restrict__ bpre, int N) {
    int i = blockIdx.x * 1024 + threadIdx.x;
    if (i < N) rowptr[i + 1] += bpre[blockIdx.x];
    if (i == 0) rowptr[0] = 0;
}
__global__ void copy_int_kernel(int* dstp, const int* __restrict__ srcp, int N) {
    int i = blockIdx.x * 256 + threadIdx.x;
    if (i < N) dstp[i] = srcp[i];
}
__global__ void fill_csr_kernel(const int* __restrict__ src, const int* __restrict__ dst,
    const float* __restrict__ dinv, int* cursor, int2* __restrict__ csre, int E)
{
    int e = blockIdx.x * 256 + threadIdx.x;
    if (e < E) {
        int d = dst[e], s = src[e];
        int p = atomicAdd(&cursor[d], 1);
        csre[p] = make_int2(s, __float_as_int(dinv[s] * dinv[d]));
    }
}

// ---------------- AMP iteration: one wave per node, barrier-free ----------------
__global__ __launch_bounds__(256, 8) void amp2_kernel(
    const float* __restrict__ xk, const float* __restrict__ hh,
    const int* __restrict__ rowptr, const int2* __restrict__ csre,
    const float* __restrict__ dinv,
    float* __restrict__ xk_new, float* __restrict__ lsm_out,
    float* __restrict__ score_out, int N, int last)
{
    int wid = (blockIdx.x * 256 + threadIdx.x) >> 6;   // node
    int lane = threadIdx.x & 63;
    if (wid >= N) return;
    const bool vf = lane < NC;
    const int cf = vf ? lane : (NC - 1);
    const size_t base = (size_t)wid * NC;
    float di = dinv[wid];
    float acc = di * di * xk[base + cf];
    int e0 = rowptr[wid], e1 = rowptr[wid + 1];
    int e = e0;
    for (; e + 1 < e1; e += 2) {
        int2 p0 = csre[e];
        int2 p1 = csre[e + 1];
        float v0 = xk[(size_t)p0.x * NC + cf];
        float v1 = xk[(size_t)p1.x * NC + cf];
        acc += __int_as_float(p0.y) * v0;
        acc += __int_as_float(p1.y) * v1;
    }
    if (e < e1) {
        int2 p = csre[e];
        acc += __int_as_float(p.y) * xk[(size_t)p.x * NC + cf];
    }
    float hv = hh[base + cf];
    float diff = acc - hv;                      // y = prop (coef == 1 exactly)
    float d2 = vf ? diff * diff : 0.f;
    #pragma unroll
    for (int off = 32; off; off >>= 1) d2 += __shfl_xor(d2, off);
    float rn = sqrtf(d2);
    float sc = (rn > LAMW) ? (rn - LAMW) / rn : 0.f;
    float xn = hv + sc * diff;
    if (!last) {
        if (vf) xk_new[base + lane] = xn;
    } else {
        if (lane == 0) score_out[wid] = sc;
        float mv = vf ? xn : -3.4e38f;
        #pragma unroll
        for (int off = 32; off; off >>= 1) mv = fmaxf(mv, __shfl_xor(mv, off));
        float ev = vf ? expf(xn - mv) : 0.f;
        #pragma unroll
        for (int off = 32; off; off >>= 1) ev += __shfl_xor(ev, off);
        float lse = mv + logf(ev);
        if (vf) lsm_out[base + lane] = xn - lse;
    }
}

extern "C" void kernel_launch(void* const* d_in, const int* in_sizes, int n_in,
                              void* d_out, int out_size, void* d_ws, size_t ws_size,
                              hipStream_t stream)
{
    const float* x  = (const float*)d_in[0];
    const float* W1 = (const float*)d_in[1];
    const float* b1 = (const float*)d_in[2];
    const float* W2 = (const float*)d_in[3];
    const float* b2 = (const float*)d_in[4];
    const int* esrc = (const int*)d_in[5];
    const int* edst = (const int*)d_in[6];
    const int N = in_sizes[0] / NF;
    const int E = in_sizes[5];

    char* W = (char*)d_ws;
    size_t o = 0;
    float* hh   = (float*)(W + o); o += (size_t)N * NC * 4;
    float* xb0  = (float*)(W + o); o += (size_t)N * NC * 4;
    float* xb1  = (float*)(W + o); o += (size_t)N * NC * 4;
    float* dinv = (float*)(W + o); o += (size_t)N * 4;
    int* rowptr = (int*)(W + o);   o += (size_t)(N + 1) * 4;
    int* cnt    = (int*)(W + o);   o += (size_t)N * 4;
    int* bsum   = (int*)(W + o);   o += 256 * 4;
    o = (o + 15) & ~(size_t)15;
    int2* csre  = (int2*)(W + o);  o += (size_t)E * 8;
    unsigned short* W1tH = (unsigned short*)(W + o); o += (size_t)NH * KPAD * 2;
    unsigned short* W1tL = (unsigned short*)(W + o); o += (size_t)NH * KPAD * 2;
    unsigned short* W2tH = (unsigned short*)(W + o); o += (size_t)NCPAD * NH * 2;
    unsigned short* W2tL = (unsigned short*)(W + o); o += (size_t)NCPAD * NH * 2;

    float* lsm = (float*)d_out;
    float* sco = lsm + (size_t)N * NC;

    const int gb = (N + 255) / 256;
    const int ge = (E + 255) / 256;
    const int nb = (N + 1023) / 1024;

    w1prep_kernel<<<KPAD, NH, 0, stream>>>(W1, W1tH, W1tL);
    w2prep_kernel<<<NCPAD, NH, 0, stream>>>(W2, W2tH, W2tL);
    mlp_mfma_kernel<<<(N + 63) / 64, 256, 0, stream>>>(x, b1, W1tH, W1tL, W2tH, W2tL, b2, hh, N);

    zero_int_kernel<<<gb, 256, 0, stream>>>(cnt, N);
    cnt_edges_kernel<<<ge, 256, 0, stream>>>(edst, cnt, E);
    dinv_kernel<<<gb, 256, 0, stream>>>(cnt, dinv, N);
    scanA_kernel<<<nb, 1024, 0, stream>>>(cnt, rowptr, bsum, N);
    scanB_kernel<<<1, 256, 0, stream>>>(bsum, nb);
    scanC_kernel<<<nb, 1024, 0, stream>>>(rowptr, bsum, N);
    copy_int_kernel<<<gb, 256, 0, stream>>>(cnt, rowptr, N);
    fill_csr_kernel<<<ge, 256, 0, stream>>>(esrc, edst, dinv, cnt, csre, E);

    const float* xold = hh;
    float* bufs[2] = {xb0, xb1};
    for (int k = 0; k < KIT; k++) {
        int last = (k == KIT - 1);
        float* xnew = bufs[k & 1];
        amp2_kernel<<<(N + 3) / 4, 256, 0, stream>>>(
            xold, hh, rowptr, csre, dinv, xnew, lsm, sco, N, last);
        xold = xnew;
    }
}

// Round 5
// 1249.525 us; speedup vs baseline: 2.6199x; 1.3252x over previous
//
#include <hip/hip_runtime.h>
#include <math.h>

#define NF 500
#define KPAD 512
#define NH 256
#define NC 40
#define NCPAD 48
#define PD 64        // padded feature row (floats)
#define KIT 10
#define LAMW 0.5f

typedef __attribute__((ext_vector_type(8))) short short8;
typedef __attribute__((ext_vector_type(4))) float f32x4;

__device__ __forceinline__ unsigned short bf_rne(float v) {
    unsigned int b = __float_as_uint(v);
    unsigned int h = (b + 0x7FFFu + ((b >> 16) & 1u)) >> 16;
    return (unsigned short)h;
}

// ---------------- weight prepass: transpose + bf16 hi/lo split ----------------
__global__ void w1prep_kernel(const float* __restrict__ W1, unsigned short* __restrict__ H,
                              unsigned short* __restrict__ L) {
    int k = blockIdx.x;        // 0..511
    int c = threadIdx.x;       // 0..255
    float v = (k < NF) ? W1[(size_t)k * NH + c] : 0.f;
    unsigned short h = bf_rne(v);
    float hf = __uint_as_float(((unsigned int)h) << 16);
    unsigned short lo = bf_rne(v - hf);
    H[(size_t)c * KPAD + k] = h;
    L[(size_t)c * KPAD + k] = lo;
}
__global__ void w2prep_kernel(const float* __restrict__ W2, unsigned short* __restrict__ H,
                              unsigned short* __restrict__ L) {
    int c = blockIdx.x;        // 0..47
    int k = threadIdx.x;       // 0..255
    float v = (c < NC) ? W2[(size_t)k * NC + c] : 0.f;
    unsigned short h = bf_rne(v);
    float hf = __uint_as_float(((unsigned int)h) << 16);
    unsigned short lo = bf_rne(v - hf);
    H[(size_t)c * NH + k] = h;
    L[(size_t)c * NH + k] = lo;
}

// ---------------- fused MLP via split-bf16 MFMA ----------------
// block = 256 thr (4 waves), 64 rows/block. Double-buffered A LDS, 1 barrier/tile.
__device__ __forceinline__ void mlp_load_tile(const float* __restrict__ xrow, int gr, int N,
                                              int skof, int tt, float v[8]) {
    if (gr < N && tt < 15) {
        float4 a = *(const float4*)(xrow + tt * 32);
        float4 b = *(const float4*)(xrow + tt * 32 + 4);
        v[0]=a.x; v[1]=a.y; v[2]=a.z; v[3]=a.w; v[4]=b.x; v[5]=b.y; v[6]=b.z; v[7]=b.w;
    } else {
        #pragma unroll
        for (int j = 0; j < 8; j++) {
            int k = tt * 32 + skof + j;
            v[j] = (gr < N && k < NF) ? xrow[tt * 32 + j] : 0.f;
        }
    }
}

__global__ __launch_bounds__(256, 2) void mlp_mfma_kernel(
    const float* __restrict__ x, const float* __restrict__ b1,
    const unsigned short* __restrict__ W1tH, const unsigned short* __restrict__ W1tL,
    const unsigned short* __restrict__ W2tH, const unsigned short* __restrict__ W2tL,
    const float* __restrict__ b2, float* __restrict__ hout, int N)
{
    __shared__ unsigned short smem[33792];     // 67.6 KB
    // phase1: A double-buffer: buf b at b*5120 (hi), +2560 (lo). [64][40] each.
    // phase2: Hhi = smem[0..], Hlo = smem + 64*264
    unsigned short* Hhi = smem;
    unsigned short* Hlo = smem + 64 * 264;

    const int t   = threadIdx.x;
    const int w   = t >> 6;
    const int l   = t & 63;
    const int l15 = l & 15;
    const int lq  = l >> 4;
    const int row0 = blockIdx.x * 64;

    f32x4 acc[4][4];
    #pragma unroll
    for (int r = 0; r < 4; r++)
        #pragma unroll
        for (int c = 0; c < 4; c++) acc[r][c] = (f32x4){0.f, 0.f, 0.f, 0.f};

    const int srow = t >> 2;          // staging row 0..63
    const int skof = (t & 3) * 8;     // staging k-offset 0/8/16/24
    const int gr = row0 + srow;
    const float* xrow = x + (size_t)gr * NF + skof;

    float v_cur[8], v_nxt[8], v_p[8];
    mlp_load_tile(xrow, gr, N, skof, 0, v_cur);
    mlp_load_tile(xrow, gr, N, skof, 1, v_nxt);

    // convert+store tile0 -> buf0
    {
        short8 sh, sl;
        #pragma unroll
        for (int j = 0; j < 8; j++) {
            unsigned int b = __float_as_uint(v_cur[j]);
            unsigned int h = (b + 0x7FFFu + ((b >> 16) & 1u)) >> 16;
            float hf = __uint_as_float(h << 16);
            float rr = v_cur[j] - hf;
            unsigned int rb = __float_as_uint(rr);
            unsigned int lo = (rb + 0x7FFFu + ((rb >> 16) & 1u)) >> 16;
            sh[j] = (short)h; sl[j] = (short)lo;
        }
        *(short8*)&smem[0 * 5120 + srow * 40 + skof] = sh;
        *(short8*)&smem[0 * 5120 + 2560 + srow * 40 + skof] = sl;
    }
    __syncthreads();

    const size_t bB = (size_t)(64 * w + l15) * KPAD + lq * 8;   // W1t lane base
    for (int kt = 0; kt < 16; ++kt) {
        const int cur = kt & 1;
        // fragments of tile kt from buf[cur]
        short8 ah[4], al[4], bh[4], bl[4];
        #pragma unroll
        for (int r = 0; r < 4; r++) {
            ah[r] = *(short8*)&smem[cur * 5120 + (16 * r + l15) * 40 + lq * 8];
            al[r] = *(short8*)&smem[cur * 5120 + 2560 + (16 * r + l15) * 40 + lq * 8];
        }
        #pragma unroll
        for (int c = 0; c < 4; c++) {
            bh[c] = *(const short8*)&W1tH[bB + (size_t)c * 16 * KPAD + kt * 32];
            bl[c] = *(const short8*)&W1tL[bB + (size_t)c * 16 * KPAD + kt * 32];
        }
        // prefetch tile kt+2 (global, overlaps MFMA)
        if (kt < 14) mlp_load_tile(xrow, gr, N, skof, kt + 2, v_p);
        // convert+store tile kt+1 -> buf[cur^1] (overlaps MFMA)
        if (kt < 15) {
            short8 sh, sl;
            #pragma unroll
            for (int j = 0; j < 8; j++) {
                unsigned int b = __float_as_uint(v_nxt[j]);
                unsigned int h = (b + 0x7FFFu + ((b >> 16) & 1u)) >> 16;
                float hf = __uint_as_float(h << 16);
                float rr = v_nxt[j] - hf;
                unsigned int rb = __float_as_uint(rr);
                unsigned int lo = (rb + 0x7FFFu + ((rb >> 16) & 1u)) >> 16;
                sh[j] = (short)h; sl[j] = (short)lo;
            }
            *(short8*)&smem[(cur ^ 1) * 5120 + srow * 40 + skof] = sh;
            *(short8*)&smem[(cur ^ 1) * 5120 + 2560 + srow * 40 + skof] = sl;
        }
        #pragma unroll
        for (int c = 0; c < 4; c++)
            #pragma unroll
            for (int r = 0; r < 4; r++) {
                acc[r][c] = __builtin_amdgcn_mfma_f32_16x16x32_bf16(ah[r], bh[c], acc[r][c], 0, 0, 0);
                acc[r][c] = __builtin_amdgcn_mfma_f32_16x16x32_bf16(al[r], bh[c], acc[r][c], 0, 0, 0);
                acc[r][c] = __builtin_amdgcn_mfma_f32_16x16x32_bf16(ah[r], bl[c], acc[r][c], 0, 0, 0);
            }
        __syncthreads();
        if (kt < 14) {
            #pragma unroll
            for (int j = 0; j < 8; j++) v_nxt[j] = v_p[j];
        }
    }

    // bias + relu + hi/lo split -> H LDS
    #pragma unroll
    for (int c = 0; c < 4; c++) {
        int col = 64 * w + 16 * c + l15;
        float bb = b1[col];
        #pragma unroll
        for (int r = 0; r < 4; r++) {
            #pragma unroll
            for (int g = 0; g < 4; g++) {
                float hval = fmaxf(acc[r][c][g] + bb, 0.f);
                unsigned int hb = __float_as_uint(hval);
                unsigned int h = (hb + 0x7FFFu + ((hb >> 16) & 1u)) >> 16;
                float hf = __uint_as_float(h << 16);
                float rr = hval - hf;
                unsigned int rb = __float_as_uint(rr);
                unsigned int lo = (rb + 0x7FFFu + ((rb >> 16) & 1u)) >> 16;
                int rowi = 16 * r + lq * 4 + g;
                Hhi[rowi * 264 + col] = (unsigned short)h;
                Hlo[rowi * 264 + col] = (unsigned short)lo;
            }
        }
    }
    __syncthreads();

    // GEMM2: out^T = W2t @ h1^T  (per wave: 16 nodes, 48 classes)
    f32x4 acc2[3];
    #pragma unroll
    for (int cf = 0; cf < 3; cf++) acc2[cf] = (f32x4){0.f, 0.f, 0.f, 0.f};
    const int hbase = (16 * w + l15) * 264 + lq * 8;
    const int wbase = l15 * NH + lq * 8;
    #pragma unroll
    for (int kt = 0; kt < 8; ++kt) {
        short8 bh = *(short8*)&Hhi[hbase + kt * 32];
        short8 bl = *(short8*)&Hlo[hbase + kt * 32];
        #pragma unroll
        for (int cf = 0; cf < 3; cf++) {
            short8 awh = *(const short8*)&W2tH[wbase + cf * 16 * NH + kt * 32];
            short8 awl = *(const short8*)&W2tL[wbase + cf * 16 * NH + kt * 32];
            acc2[cf] = __builtin_amdgcn_mfma_f32_16x16x32_bf16(awh, bh, acc2[cf], 0, 0, 0);
            acc2[cf] = __builtin_amdgcn_mfma_f32_16x16x32_bf16(awl, bh, acc2[cf], 0, 0, 0);
            acc2[cf] = __builtin_amdgcn_mfma_f32_16x16x32_bf16(awh, bl, acc2[cf], 0, 0, 0);
        }
    }
    int node = row0 + 16 * w + l15;
    if (node < N) {
        size_t ob = (size_t)node * PD;
        #pragma unroll
        for (int cf = 0; cf < 3; cf++) {
            #pragma unroll
            for (int g = 0; g < 4; g++) {
                int cls = 16 * cf + lq * 4 + g;
                hout[ob + cls] = (cls < NC) ? (acc2[cf][g] + b2[cls]) : 0.f;
            }
        }
        #pragma unroll
        for (int g = 0; g < 4; g++) hout[ob + 48 + lq * 4 + g] = 0.f;   // pad 48..63
    }
}

// ---------------- setup ----------------
__global__ void zero_int_kernel(int* p, int N) {
    int i = blockIdx.x * 256 + threadIdx.x;
    if (i < N) p[i] = 0;
}
__global__ void cnt_edges_kernel(const int* __restrict__ dst, int* cnt, int E) {
    int e = blockIdx.x * 256 + threadIdx.x;
    if (e < E) atomicAdd(&cnt[dst[e]], 1);
}
__global__ void dinv_kernel(const int* __restrict__ cnt, float* dinv, int N) {
    int i = blockIdx.x * 256 + threadIdx.x;
    if (i < N) dinv[i] = rsqrtf((float)cnt[i] + 1.0f);
}
__global__ __launch_bounds__(1024) void scanA_kernel(
    const int* __restrict__ cnt, int* __restrict__ rowptr, int* __restrict__ bsum, int N)
{
    __shared__ int sd[1024];
    int t = threadIdx.x;
    int i = blockIdx.x * 1024 + t;
    sd[t] = (i < N) ? (cnt[i] + 1) : 0;        // +1: self-loop entry
    __syncthreads();
    for (int off = 1; off < 1024; off <<= 1) {
        int v = (t >= off) ? sd[t - off] : 0;
        __syncthreads();
        if (t >= off) sd[t] += v;
        __syncthreads();
    }
    if (i < N) rowptr[i + 1] = sd[t];
    if (t == 1023) bsum[blockIdx.x] = sd[1023];
}
__global__ void scanB_kernel(int* bsum, int nb) {
    __shared__ int sb[256];
    int t = threadIdx.x;
    sb[t] = (t < nb) ? bsum[t] : 0;
    __syncthreads();
    if (t == 0) { int run = 0; for (int i = 0; i < nb; i++) { int v = sb[i]; sb[i] = run; run += v; } }
    __syncthreads();
    if (t < nb) bsum[t] = sb[t];
}
__global__ __launch_bounds__(1024) void scanC_kernel(int* rowptr, const int* __restrict__ bpre, int N) {
    int i = blockIdx.x * 1024 + threadIdx.x;
    if (i < N) rowptr[i + 1] += bpre[blockIdx.x];
    if (i == 0) rowptr[0] = 0;
}
__global__ void self_fill_kernel(const int* __restrict__ rowptr, const float* __restrict__ dinv,
                                 int2* __restrict__ csre, int* __restrict__ cursor, int N) {
    int i = blockIdx.x * 256 + threadIdx.x;
    if (i < N) {
        int p = rowptr[i];
        float d = dinv[i];
        csre[p] = make_int2(i, __float_as_int(d * d));
        cursor[i] = p + 1;
    }
}
__global__ void fill_csr_kernel(const int* __restrict__ src, const int* __restrict__ dst,
    const float* __restrict__ dinv, int* cursor, int2* __restrict__ csre, int E)
{
    int e = blockIdx.x * 256 + threadIdx.x;
    if (e < E) {
        int d = dst[e], s = src[e];
        int p = atomicAdd(&cursor[d], 1);
        csre[p] = make_int2(s, __float_as_int(dinv[s] * dinv[d]));
    }
}

// ---------------- AMP iteration: wave/node, 4-edge concurrent float4 gathers ----------------
// lane l: g = l>>4 edge slot, j = l&15 float4 slot (features 4j..4j+3, rows padded to 64)
__global__ __launch_bounds__(256, 8) void amp3_kernel(
    const float* __restrict__ xk, const float* __restrict__ hh,
    const int* __restrict__ rowptr, const int2* __restrict__ csre,
    float* __restrict__ xk_new, float* __restrict__ lsm_out,
    float* __restrict__ score_out, int N, int last)
{
    const int n = (blockIdx.x * 256 + threadIdx.x) >> 6;
    if (n >= N) return;
    const int l = threadIdx.x & 63;
    const int g = l >> 4;
    const int j = l & 15;

    const int e0 = rowptr[n];
    const int e1 = rowptr[n + 1];     // >= e0+1 (self)
    const int e1m1 = e1 - 1;

    float ax = 0.f, ay = 0.f, az = 0.f, aw = 0.f;
    for (int base = e0; base < e1; base += 8) {
        int ea = base + g;
        int eb = base + 4 + g;
        bool va = ea < e1;
        bool vb = eb < e1;
        int2 pa = csre[va ? ea : e1m1];
        int2 pb = csre[vb ? eb : e1m1];
        const float4 ra = *(const float4*)(xk + ((size_t)pa.x << 6) + (j << 2));
        const float4 rb = *(const float4*)(xk + ((size_t)pb.x << 6) + (j << 2));
        float wa = va ? __int_as_float(pa.y) : 0.f;
        float wb = vb ? __int_as_float(pb.y) : 0.f;
        ax += wa * ra.x + wb * rb.x;
        ay += wa * ra.y + wb * rb.y;
        az += wa * ra.z + wb * rb.z;
        aw += wa * ra.w + wb * rb.w;
    }
    // reduce across the 4 edge slots (all lanes end with full sums)
    ax += __shfl_xor(ax, 16); ay += __shfl_xor(ay, 16);
    az += __shfl_xor(az, 16); aw += __shfl_xor(aw, 16);
    ax += __shfl_xor(ax, 32); ay += __shfl_xor(ay, 32);
    az += __shfl_xor(az, 32); aw += __shfl_xor(aw, 32);

    const float4 h4 = *(const float4*)(hh + ((size_t)n << 6) + (j << 2));
    float dx = ax - h4.x, dy = ay - h4.y, dz = az - h4.z, dw = aw - h4.w;
    float d2 = dx * dx + dy * dy + dz * dz + dw * dw;     // pad features contribute 0
    #pragma unroll
    for (int off = 8; off; off >>= 1) d2 += __shfl_xor(d2, off);
    float rn = sqrtf(d2);
    float sc = (rn > LAMW) ? (rn - LAMW) / rn : 0.f;
    float4 xn;
    xn.x = h4.x + sc * dx; xn.y = h4.y + sc * dy;
    xn.z = h4.z + sc * dz; xn.w = h4.w + sc * dw;

    if (!last) {
        if (g == 0) *(float4*)(xk_new + ((size_t)n << 6) + (j << 2)) = xn;
    } else {
        if (l == 0) score_out[n] = sc;
        bool real = (j < 10);
        float m = real ? fmaxf(fmaxf(xn.x, xn.y), fmaxf(xn.z, xn.w)) : -3.4e38f;
        #pragma unroll
        for (int off = 8; off; off >>= 1) m = fmaxf(m, __shfl_xor(m, off));
        float es = real ? (expf(xn.x - m) + expf(xn.y - m) + expf(xn.z - m) + expf(xn.w - m)) : 0.f;
        #pragma unroll
        for (int off = 8; off; off >>= 1) es += __shfl_xor(es, off);
        float lse = m + logf(es);
        if (g == 0 && real) {
            float4 o;
            o.x = xn.x - lse; o.y = xn.y - lse; o.z = xn.z - lse; o.w = xn.w - lse;
            *(float4*)(lsm_out + (size_t)n * NC + (j << 2)) = o;
        }
    }
}

extern "C" void kernel_launch(void* const* d_in, const int* in_sizes, int n_in,
                              void* d_out, int out_size, void* d_ws, size_t ws_size,
                              hipStream_t stream)
{
    const float* x  = (const float*)d_in[0];
    const float* W1 = (const float*)d_in[1];
    const float* b1 = (const float*)d_in[2];
    const float* W2 = (const float*)d_in[3];
    const float* b2 = (const float*)d_in[4];
    const int* esrc = (const int*)d_in[5];
    const int* edst = (const int*)d_in[6];
    const int N = in_sizes[0] / NF;
    const int E = in_sizes[5];

    char* W = (char*)d_ws;
    size_t o = 0;
    float* hh   = (float*)(W + o); o += (size_t)N * PD * 4;    // padded [N][64]
    float* xb0  = (float*)(W + o); o += (size_t)N * PD * 4;
    float* xb1  = (float*)(W + o); o += (size_t)N * PD * 4;
    float* dinv = (float*)(W + o); o += (size_t)N * 4;
    int* rowptr = (int*)(W + o);   o += (size_t)(N + 1) * 4;
    int* cnt    = (int*)(W + o);   o += (size_t)N * 4;
    int* bsum   = (int*)(W + o);   o += 256 * 4;
    o = (o + 15) & ~(size_t)15;
    int2* csre  = (int2*)(W + o);  o += (size_t)(E + N) * 8;   // edges + self-loops
    o = (o + 15) & ~(size_t)15;
    unsigned short* W1tH = (unsigned short*)(W + o); o += (size_t)NH * KPAD * 2;
    unsigned short* W1tL = (unsigned short*)(W + o); o += (size_t)NH * KPAD * 2;
    unsigned short* W2tH = (unsigned short*)(W + o); o += (size_t)NCPAD * NH * 2;
    unsigned short* W2tL = (unsigned short*)(W + o); o += (size_t)NCPAD * NH * 2;

    float* lsm = (float*)d_out;
    float* sco = lsm + (size_t)N * NC;

    const int gb = (N + 255) / 256;
    const int ge = (E + 255) / 256;
    const int nb = (N + 1023) / 1024;

    w1prep_kernel<<<KPAD, NH, 0, stream>>>(W1, W1tH, W1tL);
    w2prep_kernel<<<NCPAD, NH, 0, stream>>>(W2, W2tH, W2tL);
    mlp_mfma_kernel<<<(N + 63) / 64, 256, 0, stream>>>(x, b1, W1tH, W1tL, W2tH, W2tL, b2, hh, N);

    zero_int_kernel<<<gb, 256, 0, stream>>>(cnt, N);
    cnt_edges_kernel<<<ge, 256, 0, stream>>>(edst, cnt, E);
    dinv_kernel<<<gb, 256, 0, stream>>>(cnt, dinv, N);
    scanA_kernel<<<nb, 1024, 0, stream>>>(cnt, rowptr, bsum, N);
    scanB_kernel<<<1, 256, 0, stream>>>(bsum, nb);
    scanC_kernel<<<nb, 1024, 0, stream>>>(rowptr, bsum, N);
    self_fill_kernel<<<gb, 256, 0, stream>>>(rowptr, dinv, csre, cnt, N);   // cnt reused as cursor
    fill_csr_kernel<<<ge, 256, 0, stream>>>(esrc, edst, dinv, cnt, csre, E);

    const float* xold = hh;
    float* bufs[2] = {xb0, xb1};
    for (int k = 0; k < KIT; k++) {
        int last = (k == KIT - 1);
        float* xnew = bufs[k & 1];
        amp3_kernel<<<(N + 3) / 4, 256, 0, stream>>>(
            xold, hh, rowptr, csre, xnew, lsm, sco, N, last);
        xold = xnew;
    }
}